// Round 2
// baseline (148.339 us; speedup 1.0000x reference)
//
#include <hip/hip_runtime.h>

// SkewedLossFunction_OneSide: mean(|y_pred - y_true| * exp(gate * |lam|))
//   lam  = y_true/50 - 1        (both reference branches collapse to this)
//   gate = 1 iff (y_true - y_pred) and lam have the same (nonzero) sign
//
// Single fused kernel: grid-stride float4 reads (64 MiB total, HBM-bound),
// block reduce, device-scope atomicAdd(double) into d_ws, last block writes
// mean to d_out. d_ws[0:8] = double accumulator, d_ws[8:12] = finish counter,
// both zeroed by a 16-byte memset node captured in the graph.

#define N_ELEM   8388608
#define NBLOCKS  2048
#define NTHREADS 256

__device__ __forceinline__ float skew1(float p, float t) {
    float base = fabsf(p - t);
    float lam  = __fmaf_rn(t, 0.02f, -1.0f);     // y/50 - 1, in [-1, 1]
    // gate==1 iff sign(t-p)*sign(lam) > 0  <=>  (t-p)*lam > 0
    float g    = ((t - p) * lam > 0.0f) ? fabsf(lam) : 0.0f;
    return base * __expf(g);                     // exponent in [0,1]
}

__global__ __launch_bounds__(NTHREADS) void skew_fused_kernel(
        const float4* __restrict__ yp,
        const float4* __restrict__ yt,
        double* __restrict__ acc,           // d_ws + 0, pre-zeroed
        unsigned int* __restrict__ counter, // d_ws + 8, pre-zeroed
        float* __restrict__ out) {
    const int tid = threadIdx.x;
    const int gid = blockIdx.x * NTHREADS + tid;
    const int stride = NBLOCKS * NTHREADS;
    const int n4 = N_ELEM / 4;

    float s = 0.0f;
    for (int i = gid; i < n4; i += stride) {
        float4 p = yp[i];
        float4 t = yt[i];
        s += skew1(p.x, t.x);
        s += skew1(p.y, t.y);
        s += skew1(p.z, t.z);
        s += skew1(p.w, t.w);
    }

    // wave-64 shuffle reduce
    #pragma unroll
    for (int off = 32; off > 0; off >>= 1)
        s += __shfl_down(s, off, 64);

    __shared__ float wsum[NTHREADS / 64];
    if ((tid & 63) == 0) wsum[tid >> 6] = s;
    __syncthreads();

    if (tid == 0) {
        float bsum = wsum[0] + wsum[1] + wsum[2] + wsum[3];
        atomicAdd(acc, (double)bsum);            // device-scope f64 atomic
        __threadfence();
        unsigned int done = atomicAdd(counter, 1u);
        if (done == NBLOCKS - 1) {
            // all-atomic read: safe across XCD L2s
            double total = atomicAdd(acc, 0.0);
            out[0] = (float)(total / (double)N_ELEM);
        }
    }
}

extern "C" void kernel_launch(void* const* d_in, const int* in_sizes, int n_in,
                              void* d_out, int out_size, void* d_ws, size_t ws_size,
                              hipStream_t stream) {
    const float4* y_pred = (const float4*)d_in[0];
    const float4* y_true = (const float4*)d_in[1];
    double*       acc     = (double*)d_ws;
    unsigned int* counter = (unsigned int*)((char*)d_ws + 8);
    float*        out     = (float*)d_out;

    hipMemsetAsync(d_ws, 0, 16, stream);  // zero acc + counter (graph-capturable)
    skew_fused_kernel<<<NBLOCKS, NTHREADS, 0, stream>>>(y_pred, y_true, acc, counter, out);
}

// Round 3
// 93.230 us; speedup vs baseline: 1.5911x; 1.5911x over previous
//
#include <hip/hip_runtime.h>

// SkewedLossFunction_OneSide: mean(|y_pred - y_true| * exp(gate * |lam|))
//   lam  = y_true/50 - 1        (both reference branches collapse to this)
//   gate = 1 iff (y_true - y_pred) and lam have the same (nonzero) sign
//
// Two-pass reduce (round-1 structure — fused single-cacheline atomics cost
// +52 us in round 2 due to the serialized cross-XCD atomic tail):
//   pass 1: 2048 blocks, grid-stride float4, block reduce, plain store of one
//           fp32 partial per block into a private d_ws slot (no atomics).
//   pass 2: 1 block sums 2048 partials in double, writes mean.

#define N_ELEM   8388608
#define NBLOCKS  2048
#define NTHREADS 256

__device__ __forceinline__ float skew1(float p, float t) {
    float base = fabsf(p - t);
    float lam  = __fmaf_rn(t, 0.02f, -1.0f);     // y/50 - 1, in [-1, 1]
    // gate==1 iff sign(t-p)*sign(lam) > 0  <=>  (t-p)*lam > 0
    float g    = ((t - p) * lam > 0.0f) ? fabsf(lam) : 0.0f;
    return base * __expf(g);                     // exponent in [0,1]
}

__device__ __forceinline__ float skew4(float4 p, float4 t) {
    return skew1(p.x, t.x) + skew1(p.y, t.y) + skew1(p.z, t.z) + skew1(p.w, t.w);
}

__global__ __launch_bounds__(NTHREADS) void skew_partial_kernel(
        const float4* __restrict__ yp,
        const float4* __restrict__ yt,
        float* __restrict__ partial) {
    const int tid = threadIdx.x;
    const int gid = blockIdx.x * NTHREADS + tid;
    const int stride = NBLOCKS * NTHREADS;
    const int n4 = N_ELEM / 4;     // 2097152; 4 grid-stride iters -> 2 unrolled

    float acc = 0.0f;
    // n4 / stride == 4 exactly; unroll 2x so 4 loads (2 p + 2 t) are in flight.
    for (int i = gid; i < n4; i += 2 * stride) {
        float4 p0 = yp[i];
        float4 t0 = yt[i];
        float4 p1 = yp[i + stride];
        float4 t1 = yt[i + stride];
        acc += skew4(p0, t0);
        acc += skew4(p1, t1);
    }

    // wave-64 shuffle reduce
    #pragma unroll
    for (int off = 32; off > 0; off >>= 1)
        acc += __shfl_down(acc, off, 64);

    __shared__ float wsum[NTHREADS / 64];
    if ((tid & 63) == 0) wsum[tid >> 6] = acc;
    __syncthreads();
    if (tid == 0) {
        partial[blockIdx.x] = wsum[0] + wsum[1] + wsum[2] + wsum[3];
    }
}

__global__ __launch_bounds__(256) void skew_final_kernel(
        const float* __restrict__ partial,
        float* __restrict__ out) {
    const int tid = threadIdx.x;
    double acc = 0.0;
    #pragma unroll
    for (int i = tid; i < NBLOCKS; i += 256)
        acc += (double)partial[i];

    #pragma unroll
    for (int off = 32; off > 0; off >>= 1)
        acc += __shfl_down(acc, off, 64);

    __shared__ double wsum[256 / 64];
    if ((tid & 63) == 0) wsum[tid >> 6] = acc;
    __syncthreads();
    if (tid == 0) {
        double s = wsum[0] + wsum[1] + wsum[2] + wsum[3];
        out[0] = (float)(s / (double)N_ELEM);
    }
}

extern "C" void kernel_launch(void* const* d_in, const int* in_sizes, int n_in,
                              void* d_out, int out_size, void* d_ws, size_t ws_size,
                              hipStream_t stream) {
    const float4* y_pred = (const float4*)d_in[0];
    const float4* y_true = (const float4*)d_in[1];
    float* partial = (float*)d_ws;          // NBLOCKS * 4 B = 8 KiB
    float* out     = (float*)d_out;

    skew_partial_kernel<<<NBLOCKS, NTHREADS, 0, stream>>>(y_pred, y_true, partial);
    skew_final_kernel<<<1, 256, 0, stream>>>(partial, out);
}